// Round 7
// baseline (524.491 us; speedup 1.0000x reference)
//
#include <hip/hip_runtime.h>
#include <math.h>

#define N_EDGES   1048576
#define N_BUCKET  1024          // bucket = seg >> 7 (128 segs / bucket)
#define SEG_PER_B 128
#define N_BASIS   12
#define CAP       1280          // per-bucket edge capacity (Poisson(1024), max~1150)
#define HBLK      64            // hist/partition blocks (1024 threads each)
#define HEPB      (N_EDGES / HBLK)   // 16384 edges per hist/partition block

// rec = (sl << 20) | edge_id   (sl = seg & 127, edge_id < 2^20)

// ---- workspace layout (contention-free counting sort; no memset needed) ----
#define WS_BLKHIST  0                             // int[HBLK][N_BUCKET]  (256 KB)
#define WS_TOTALS   (HBLK * N_BUCKET * 4)         // int[N_BUCKET]
#define WS_OFFSETS  (WS_TOTALS + N_BUCKET * 4)    // int[N_BUCKET]
#define WS_RECORDS  (WS_OFFSETS + N_BUCKET * 4)   // u32[N_EDGES]  (4 MB)
#define WS_NEEDED   (WS_RECORDS + N_EDGES * 4)

__device__ __forceinline__ void compute_edge(float x, float y, float z,
                                             float* __restrict__ ph,   // 12, scaled by NORM/r
                                             float* __restrict__ sh)   // 16
{
    const float r2    = fmaf(x, x, fmaf(y, y, z * z)) + 1e-12f;
    const float inv_r = rsqrtf(r2);
    const float r     = r2 * inv_r;
    x *= inv_r; y *= inv_r; z *= inv_r;

    const float t = 0.6283185307179586f * r;   // pi/5 * r
    float s1, c1;
    __sincosf(t, &s1, &c1);
    const float twoc = 2.0f * c1;
    const float scale = 0.17677669529663687f * inv_r;  // (1/sqrt(32)) / r
    float skm1 = 0.0f, sk = s1;
    #pragma unroll
    for (int b = 0; b < N_BASIS; ++b) {
        ph[b] = sk * scale;
        const float nxt = fmaf(twoc, sk, -skm1);
        skm1 = sk; sk = nxt;
    }

    const float x2 = x * x, y2 = y * y, z2 = z * z;
    sh[0]  = 0.28209479177387814f;
    sh[1]  = 0.4886025119029199f * y;
    sh[2]  = 0.4886025119029199f * z;
    sh[3]  = 0.4886025119029199f * x;
    sh[4]  = 1.0925484305920792f * x * y;
    sh[5]  = 1.0925484305920792f * y * z;
    sh[6]  = 0.31539156525252005f * (3.0f * z2 - 1.0f);
    sh[7]  = 1.0925484305920792f * x * z;
    sh[8]  = 0.5462742152960396f * (x2 - y2);
    sh[9]  = 0.5900435899266435f * y * (3.0f * x2 - y2);
    sh[10] = 2.890611442640554f  * x * y * z;
    sh[11] = 0.4570457994644658f * y * (5.0f * z2 - 1.0f);
    sh[12] = 0.3731763325901154f * (5.0f * z2 * z - 3.0f * z);
    sh[13] = 0.4570457994644658f * x * (5.0f * z2 - 1.0f);
    sh[14] = 1.445305721320277f  * z * (x2 - y2);
    sh[15] = 0.5900435899266435f * x * (x2 - y2);
}

__device__ __forceinline__ void accum_edge(const float4 v,
                                           const float (&Wn)[4][N_BASIS],
                                           float* __restrict__ acc)
{
    float ph[N_BASIS], sh[16];
    compute_edge(v.x, v.y, v.z, ph, sh);
    float rad[4];
    #pragma unroll
    for (int l = 0; l < 4; ++l) {
        float a = 0.0f;
        #pragma unroll
        for (int bb = 0; bb < N_BASIS; ++bb)
            a = fmaf(ph[bb], Wn[l][bb], a);
        rad[l] = a;
    }
    #pragma unroll
    for (int L = 0; L < 16; ++L) {
        const int l = (L == 0) ? 0 : (L < 4) ? 1 : (L < 9) ? 2 : 3;
        acc[L] = fmaf(sh[L], rad[l], acc[L]);
    }
}

__device__ __forceinline__ void flush_seg(const float* __restrict__ acc,
                                          int b, int sl, int n,
                                          float* __restrict__ out)
{
    const int seg = b * SEG_PER_B + sl;
    float* op = out + (size_t)(seg >> 2) * 512 + (seg & 3) * 8 + n;
    #pragma unroll
    for (int L = 0; L < 16; ++L) op[L * 32] = acc[L];
}

// ---------- 1: per-block histogram (LDS only; coalesced writeout; no global atomics) ----------
__global__ __launch_bounds__(1024) void hist_kernel(
    const int* __restrict__ cidx, const int* __restrict__ sidx,
    int* __restrict__ blkhist)
{
    __shared__ int h[N_BUCKET];
    const int t = threadIdx.x;
    h[t] = 0;
    __syncthreads();
    const int base = blockIdx.x * HEPB;
    #pragma unroll
    for (int k = 0; k < HEPB / 1024; ++k) {
        const int e = base + k * 1024 + t;
        const int seg = (cidx[e] << 2) | sidx[e];
        atomicAdd(&h[seg >> 7], 1);
    }
    __syncthreads();
    blkhist[blockIdx.x * N_BUCKET + t] = h[t];
}

// ---------- 2: partition with fused scan (each block redundantly scans blkhist) ----------
__global__ __launch_bounds__(1024) void partition_kernel(
    const int* __restrict__ cidx, const int* __restrict__ sidx,
    const int* __restrict__ blkhist,
    unsigned int* __restrict__ records,
    int* __restrict__ offsets_g, int* __restrict__ totals_g)
{
    __shared__ int scan_s[N_BUCKET];
    __shared__ int bb[N_BUCKET];     // global write base for this (block,bucket)
    __shared__ int lcnt[N_BUCKET];
    const int t  = threadIdx.x;      // one thread per bucket
    const int me = blockIdx.x;

    // column pass: total over all hist blocks, partial sum over blocks < me
    int total = 0, before = 0;
    for (int blk = 0; blk < HBLK; ++blk) {
        const int v = blkhist[blk * N_BUCKET + t];   // coalesced row reads
        total += v;
        if (blk < me) before += v;
    }
    scan_s[t] = total;
    __syncthreads();
    #pragma unroll
    for (int d = 1; d < N_BUCKET; d <<= 1) {
        const int v = (t >= d) ? scan_s[t - d] : 0;
        __syncthreads();
        scan_s[t] += v;
        __syncthreads();
    }
    const int gbase = scan_s[t] - total;             // exclusive bucket offset
    bb[t]   = gbase + before;
    lcnt[t] = 0;
    if (me == 0) { offsets_g[t] = gbase; totals_g[t] = total; }
    __syncthreads();

    const int base = me * HEPB;
    #pragma unroll
    for (int k = 0; k < HEPB / 1024; ++k) {
        const int e = base + k * 1024 + t;
        const int seg = (cidx[e] << 2) | sidx[e];
        const int bkt = seg >> 7;
        const int r = atomicAdd(&lcnt[bkt], 1);
        records[bb[bkt] + r] = ((unsigned)(seg & 127) << 20) | (unsigned)e;
    }
}

// ---------- 3: compute — 512 threads, 64 groups x 2 segs; LDS sort + register-acc walk ----------
__global__ __launch_bounds__(512, 8) void compute_kernel(
    const unsigned int* __restrict__ sorted_rec,
    const int* __restrict__ offsets, const int* __restrict__ counts,
    const float* __restrict__ vectors,
    const float* __restrict__ rw,    // (4,12,8)
    float* __restrict__ out)
{
    __shared__ float4 pay[CAP];                 // 20 KB
    __shared__ int shist[SEG_PER_B];
    __shared__ int soff[SEG_PER_B + 1];         // +1 sentinel = cnt
    __shared__ int scur[SEG_PER_B];

    const int t = threadIdx.x;
    const int b = blockIdx.x;
    const int n = t & 7;                        // radial index owned by this lane
    const int g = t >> 3;                       // group 0..63; owns segments 2g, 2g+1

    // per-lane W slice: Wn[l][bb] = rw[(l*12+bb)*8 + n]
    float Wn[4][N_BASIS];
    #pragma unroll
    for (int l = 0; l < 4; ++l)
        #pragma unroll
        for (int bb = 0; bb < N_BASIS; ++bb)
            Wn[l][bb] = rw[(l * N_BASIS + bb) * 8 + n];

    const int off = offsets[b];
    const int cnt = counts[b];

    if (cnt > CAP) {
        // correctness-only slow path (P ~ 1e-15 per bucket)
        #pragma unroll 1
        for (int k = 0; k < 2; ++k) {
            const int sl = g * 2 + k;
            float acc[16];
            #pragma unroll
            for (int L = 0; L < 16; ++L) acc[L] = 0.0f;
            for (int j = 0; j < cnt; ++j) {
                const unsigned rec = sorted_rec[off + j];
                if ((int)(rec >> 20) != sl) continue;
                const int eid = rec & 0xFFFFF;
                const float4 v = make_float4(vectors[3*eid], vectors[3*eid+1],
                                             vectors[3*eid+2], 0.0f);
                accum_edge(v, Wn, acc);
            }
            flush_seg(acc, b, sl, n, out);
        }
        return;
    }

    if (t < SEG_PER_B) shist[t] = 0;
    __syncthreads();

    // stage recs in registers + histogram by local segment
    unsigned recs[3];
    const int iters = (cnt + 511) >> 9;         // <= 3
    #pragma unroll
    for (int it = 0; it < 3; ++it) {
        const int i = it * 512 + t;
        if (it < iters && i < cnt) {
            recs[it] = sorted_rec[off + i];
            atomicAdd(&shist[recs[it] >> 20], 1);
        }
    }
    __syncthreads();

    // exclusive scan of shist (128 entries)
    if (t < SEG_PER_B) soff[t] = shist[t];
    __syncthreads();
    #pragma unroll
    for (int d = 1; d < SEG_PER_B; d <<= 1) {
        int v = 0;
        if (t >= d && t < SEG_PER_B) v = soff[t - d];
        __syncthreads();
        if (t < SEG_PER_B) soff[t] += v;
        __syncthreads();
    }
    if (t < SEG_PER_B) {
        const int ex = soff[t] - shist[t];
        soff[t] = ex;
        scur[t] = ex;
    }
    if (t == SEG_PER_B) soff[SEG_PER_B] = cnt;  // sentinel
    __syncthreads();

    // place: rank + gather xyz from L2/L3-resident vectors
    #pragma unroll
    for (int it = 0; it < 3; ++it) {
        const int i = it * 512 + t;
        if (it < iters && i < cnt) {
            const unsigned rec = recs[it];
            const int sl  = rec >> 20;
            const int eid = rec & 0xFFFFF;
            const int r = atomicAdd(&scur[sl], 1);
            pay[r] = make_float4(vectors[3 * eid], vectors[3 * eid + 1],
                                 vectors[3 * eid + 2], __int_as_float(sl));
        }
    }
    __syncthreads();

    // walk: group g covers the concatenated edges of segments 2g, 2g+1
    const int s0 = g * 2;
    const int js = soff[s0];
    const int je = soff[s0 + 2];

    int cur = -1;
    float acc[16];
    #pragma unroll
    for (int L = 0; L < 16; ++L) acc[L] = 0.0f;

    for (int j = js; j < je; ++j) {
        const float4 v = pay[j];                // 8-lane broadcast b128
        const int sl = __float_as_int(v.w);
        if (sl != cur) {
            if (cur >= 0) {
                flush_seg(acc, b, cur, n, out);
                #pragma unroll
                for (int L = 0; L < 16; ++L) acc[L] = 0.0f;
            }
            cur = sl;
        }
        accum_edge(v, Wn, acc);
    }
    if (cur >= 0) flush_seg(acc, b, cur, n, out);

    // zero-fill empty segments (output is poisoned; every element must be written)
    #pragma unroll
    for (int k = 0; k < 2; ++k) {
        const int sl = s0 + k;
        if (shist[sl] == 0) {
            float z[16];
            #pragma unroll
            for (int L = 0; L < 16; ++L) z[L] = 0.0f;
            flush_seg(z, b, sl, n, out);
        }
    }
}

// ---------- fallback: atomic kernel (used only if ws too small) ----------
__global__ __launch_bounds__(256) void atomic_kernel(
    const float* __restrict__ vectors, const float* __restrict__ rw,
    const int* __restrict__ cidx, const int* __restrict__ sidx,
    float* __restrict__ out)
{
    const int e = blockIdx.x * 256 + threadIdx.x;
    if (e >= N_EDGES) return;
    float ph[N_BASIS], sh[16];
    compute_edge(vectors[3*e], vectors[3*e+1], vectors[3*e+2], ph, sh);
    float* op = out + (size_t)cidx[e] * 512 + sidx[e] * 8;
    for (int l = 0; l < 4; ++l) {
        const int L0 = l * l;
        const int ml = 2 * l + 1;
        for (int nn = 0; nn < 8; ++nn) {
            float rad = 0.0f;
            for (int bb = 0; bb < N_BASIS; ++bb)
                rad = fmaf(ph[bb], rw[(l * N_BASIS + bb) * 8 + nn], rad);
            for (int mm = 0; mm < ml; ++mm)
                atomicAdd(op + (L0 + mm) * 32 + nn, sh[L0 + mm] * rad);
        }
    }
}

extern "C" void kernel_launch(void* const* d_in, const int* in_sizes, int n_in,
                              void* d_out, int out_size, void* d_ws, size_t ws_size,
                              hipStream_t stream) {
    const float* vectors = (const float*)d_in[0];
    const float* rw      = (const float*)d_in[1];
    const int*   cidx    = (const int*)d_in[2];
    const int*   sidx    = (const int*)d_in[3];
    float*       out     = (float*)d_out;

    if (ws_size < (size_t)WS_NEEDED) {
        hipMemsetAsync(out, 0, (size_t)out_size * sizeof(float), stream);
        hipLaunchKernelGGL(atomic_kernel, dim3(N_EDGES / 256), dim3(256), 0, stream,
                           vectors, rw, cidx, sidx, out);
        return;
    }

    char* ws = (char*)d_ws;
    int*          blkhist = (int*)(ws + WS_BLKHIST);
    int*          totals  = (int*)(ws + WS_TOTALS);
    int*          offsets = (int*)(ws + WS_OFFSETS);
    unsigned int* records = (unsigned int*)(ws + WS_RECORDS);

    hipLaunchKernelGGL(hist_kernel,      dim3(HBLK),     dim3(1024), 0, stream, cidx, sidx, blkhist);
    hipLaunchKernelGGL(partition_kernel, dim3(HBLK),     dim3(1024), 0, stream, cidx, sidx, blkhist, records, offsets, totals);
    hipLaunchKernelGGL(compute_kernel,   dim3(N_BUCKET), dim3(512),  0, stream, records, offsets, totals, vectors, rw, out);
}

// Round 8
// 175.349 us; speedup vs baseline: 2.9911x; 2.9911x over previous
//
#include <hip/hip_runtime.h>
#include <math.h>

#define N_EDGES   1048576
#define N_BUCKET  1024          // bucket = seg >> 7 (128 segs / bucket)
#define SEG_PER_B 128
#define N_BASIS   12
#define CAP       1536          // per-bucket edge capacity (Poisson(1024), max~1150)
#define HBLK      128           // hist/partition blocks (1024 threads each)
#define HEPB      (N_EDGES / HBLK)   // 8192 edges per hist/partition block

// ---- workspace layout ----
#define WS_BLKHIST  0                      // int[HBLK][N_BUCKET] (512 KB)
#define WS_TOTALS   524288                 // int[N_BUCKET]
#define WS_OFFSETS  528384                 // int[N_BUCKET]
#define WS_REC      532480                 // float4[N_EDGES] (16 MB)  [16-path]
                                           //   or u32[N_EDGES] (4 MB) [4-path]
#define WS_NEED16   (532480 + (size_t)N_EDGES * 16)
#define WS_NEED4    (532480 + (size_t)N_EDGES * 4)

__device__ __forceinline__ void compute_edge(float x, float y, float z,
                                             float* __restrict__ ph,   // 12, scaled by NORM/r
                                             float* __restrict__ sh)   // 16
{
    const float r2    = fmaf(x, x, fmaf(y, y, z * z)) + 1e-12f;
    const float inv_r = rsqrtf(r2);
    const float r     = r2 * inv_r;
    x *= inv_r; y *= inv_r; z *= inv_r;

    const float t = 0.6283185307179586f * r;   // pi/5 * r
    float s1, c1;
    __sincosf(t, &s1, &c1);
    const float twoc = 2.0f * c1;
    const float scale = 0.17677669529663687f * inv_r;  // (1/sqrt(32)) / r
    float skm1 = 0.0f, sk = s1;
    #pragma unroll
    for (int b = 0; b < N_BASIS; ++b) {
        ph[b] = sk * scale;
        const float nxt = fmaf(twoc, sk, -skm1);
        skm1 = sk; sk = nxt;
    }

    const float x2 = x * x, y2 = y * y, z2 = z * z;
    sh[0]  = 0.28209479177387814f;
    sh[1]  = 0.4886025119029199f * y;
    sh[2]  = 0.4886025119029199f * z;
    sh[3]  = 0.4886025119029199f * x;
    sh[4]  = 1.0925484305920792f * x * y;
    sh[5]  = 1.0925484305920792f * y * z;
    sh[6]  = 0.31539156525252005f * (3.0f * z2 - 1.0f);
    sh[7]  = 1.0925484305920792f * x * z;
    sh[8]  = 0.5462742152960396f * (x2 - y2);
    sh[9]  = 0.5900435899266435f * y * (3.0f * x2 - y2);
    sh[10] = 2.890611442640554f  * x * y * z;
    sh[11] = 0.4570457994644658f * y * (5.0f * z2 - 1.0f);
    sh[12] = 0.3731763325901154f * (5.0f * z2 * z - 3.0f * z);
    sh[13] = 0.4570457994644658f * x * (5.0f * z2 - 1.0f);
    sh[14] = 1.445305721320277f  * z * (x2 - y2);
    sh[15] = 0.5900435899266435f * x * (x2 - y2);
}

__device__ __forceinline__ void accum_edge(const float4 v,
                                           const float (&Wn)[4][N_BASIS],
                                           float* __restrict__ acc)
{
    float ph[N_BASIS], sh[16];
    compute_edge(v.x, v.y, v.z, ph, sh);
    float rad[4];
    #pragma unroll
    for (int l = 0; l < 4; ++l) {
        float a = 0.0f;
        #pragma unroll
        for (int bb = 0; bb < N_BASIS; ++bb)
            a = fmaf(ph[bb], Wn[l][bb], a);
        rad[l] = a;
    }
    #pragma unroll
    for (int L = 0; L < 16; ++L) {
        const int l = (L == 0) ? 0 : (L < 4) ? 1 : (L < 9) ? 2 : 3;
        acc[L] = fmaf(sh[L], rad[l], acc[L]);
    }
}

__device__ __forceinline__ void flush_seg(const float* __restrict__ acc,
                                          int b, int sl, int n,
                                          float* __restrict__ out)
{
    const int seg = b * SEG_PER_B + sl;
    float* op = out + (size_t)(seg >> 2) * 512 + (seg & 3) * 8 + n;
    #pragma unroll
    for (int L = 0; L < 16; ++L) op[L * 32] = acc[L];
}

// ---------- 1: per-block histogram (LDS only; no global atomics) ----------
__global__ __launch_bounds__(1024) void hist_kernel(
    const int* __restrict__ cidx, const int* __restrict__ sidx,
    int* __restrict__ blkhist)
{
    __shared__ int h[N_BUCKET];
    const int t = threadIdx.x;
    h[t] = 0;
    __syncthreads();
    const int base = blockIdx.x * HEPB;
    #pragma unroll
    for (int k = 0; k < HEPB / 1024; ++k) {
        const int e = base + k * 1024 + t;
        const int seg = (cidx[e] << 2) | sidx[e];
        atomicAdd(&h[seg >> 7], 1);
    }
    __syncthreads();
    blkhist[blockIdx.x * N_BUCKET + t] = h[t];
}

// ---------- 2a: partition with fused scan; writes 16B payload records ----------
__global__ __launch_bounds__(1024) void partition16_kernel(
    const int* __restrict__ cidx, const int* __restrict__ sidx,
    const float* __restrict__ vectors,
    const int* __restrict__ blkhist,
    float4* __restrict__ rec16,
    int* __restrict__ offsets_g, int* __restrict__ totals_g)
{
    __shared__ int scan_s[N_BUCKET];
    __shared__ int bb[N_BUCKET];
    __shared__ int lcnt[N_BUCKET];
    const int t  = threadIdx.x;      // one thread per bucket
    const int me = blockIdx.x;

    int total = 0, before = 0;
    for (int blk = 0; blk < HBLK; ++blk) {
        const int v = blkhist[blk * N_BUCKET + t];   // coalesced row reads
        total += v;
        if (blk < me) before += v;
    }
    scan_s[t] = total;
    __syncthreads();
    #pragma unroll
    for (int d = 1; d < N_BUCKET; d <<= 1) {
        const int v = (t >= d) ? scan_s[t - d] : 0;
        __syncthreads();
        scan_s[t] += v;
        __syncthreads();
    }
    const int gbase = scan_s[t] - total;
    bb[t]   = gbase + before;
    lcnt[t] = 0;
    if (me == 0) { offsets_g[t] = gbase; totals_g[t] = total; }
    __syncthreads();

    const int base = me * HEPB;
    #pragma unroll
    for (int k = 0; k < HEPB / 1024; ++k) {
        const int e = base + k * 1024 + t;
        const int seg = (cidx[e] << 2) | sidx[e];
        const int bkt = seg >> 7;
        const float x = vectors[3 * e + 0];      // coalesced (original edge order)
        const float y = vectors[3 * e + 1];
        const float z = vectors[3 * e + 2];
        const int r = atomicAdd(&lcnt[bkt], 1);
        rec16[bb[bkt] + r] = make_float4(x, y, z, __int_as_float(seg & 127));
    }
}

// ---------- 3a: compute — payload records; no vectors gather at all ----------
__global__ __launch_bounds__(256) void compute16_kernel(
    const float4* __restrict__ rec16,
    const int* __restrict__ offsets, const int* __restrict__ counts,
    const float* __restrict__ rw,    // (4,12,8)
    float* __restrict__ out)
{
    __shared__ float4 pay[CAP];                 // 24 KB
    __shared__ int shist[SEG_PER_B];
    __shared__ int soff[SEG_PER_B];
    __shared__ int scur[SEG_PER_B];

    const int t = threadIdx.x;
    const int b = blockIdx.x;
    const int n = t & 7;                        // radial index owned by this lane
    const int g = t >> 3;                       // group 0..31; owns segments 4g..4g+3

    float Wn[4][N_BASIS];
    #pragma unroll
    for (int l = 0; l < 4; ++l)
        #pragma unroll
        for (int bb = 0; bb < N_BASIS; ++bb)
            Wn[l][bb] = rw[(l * N_BASIS + bb) * 8 + n];

    const int off = offsets[b];
    const int cnt = counts[b];

    if (cnt > CAP) {
        // correctness-only slow path (P ~ 1e-20 per bucket)
        #pragma unroll 1
        for (int k = 0; k < 4; ++k) {
            const int sl = g * 4 + k;
            float acc[16];
            #pragma unroll
            for (int L = 0; L < 16; ++L) acc[L] = 0.0f;
            for (int j = 0; j < cnt; ++j) {
                const float4 v = rec16[off + j];
                if (__float_as_int(v.w) != sl) continue;
                accum_edge(v, Wn, acc);
            }
            flush_seg(acc, b, sl, n, out);
        }
        return;
    }

    if (t < SEG_PER_B) shist[t] = 0;
    __syncthreads();

    // stage payload records in registers + histogram by local segment
    float4 recs[6];
    const int iters = (cnt + 255) >> 8;         // <= 6
    #pragma unroll
    for (int it = 0; it < 6; ++it) {
        const int i = it * 256 + t;
        if (it < iters && i < cnt) {
            recs[it] = rec16[off + i];          // coalesced float4 stream
            atomicAdd(&shist[__float_as_int(recs[it].w)], 1);
        }
    }
    __syncthreads();

    // exclusive scan of shist (128 entries)
    if (t < SEG_PER_B) soff[t] = shist[t];
    __syncthreads();
    #pragma unroll
    for (int d = 1; d < SEG_PER_B; d <<= 1) {
        int v = 0;
        if (t >= d && t < SEG_PER_B) v = soff[t - d];
        __syncthreads();
        if (t < SEG_PER_B) soff[t] += v;
        __syncthreads();
    }
    if (t < SEG_PER_B) {
        const int ex = soff[t] - shist[t];
        soff[t] = ex;
        scur[t] = ex;
    }
    __syncthreads();

    // place into seg-sorted LDS order (register-held payload; no global traffic)
    #pragma unroll
    for (int it = 0; it < 6; ++it) {
        const int i = it * 256 + t;
        if (it < iters && i < cnt) {
            const int sl = __float_as_int(recs[it].w);
            const int r = atomicAdd(&scur[sl], 1);
            pay[r] = recs[it];
        }
    }
    __syncthreads();

    // fused walk: group g covers the concatenated edges of segments 4g..4g+3
    const int s0 = g * 4;
    const int js = soff[s0];
    const int je = (s0 + 4 < SEG_PER_B) ? soff[s0 + 4] : cnt;

    int cur = -1;
    float acc[16];
    #pragma unroll
    for (int L = 0; L < 16; ++L) acc[L] = 0.0f;

    for (int j = js; j < je; ++j) {
        const float4 v = pay[j];                // 8-lane broadcast b128
        const int sl = __float_as_int(v.w);
        if (sl != cur) {
            if (cur >= 0) {
                flush_seg(acc, b, cur, n, out);
                #pragma unroll
                for (int L = 0; L < 16; ++L) acc[L] = 0.0f;
            }
            cur = sl;
        }
        accum_edge(v, Wn, acc);
    }
    if (cur >= 0) flush_seg(acc, b, cur, n, out);

    // zero-fill empty segments (output is poisoned; every element must be written)
    #pragma unroll
    for (int k = 0; k < 4; ++k) {
        const int sl = s0 + k;
        if (shist[sl] == 0) {
            float z[16];
            #pragma unroll
            for (int L = 0; L < 16; ++L) z[L] = 0.0f;
            flush_seg(z, b, sl, n, out);
        }
    }
}

// ---------- 2b/3b: fallback path with 4B records (ws < 16.6 MB) ----------
__global__ __launch_bounds__(1024) void partition4_kernel(
    const int* __restrict__ cidx, const int* __restrict__ sidx,
    const int* __restrict__ blkhist,
    unsigned int* __restrict__ records,
    int* __restrict__ offsets_g, int* __restrict__ totals_g)
{
    __shared__ int scan_s[N_BUCKET];
    __shared__ int bb[N_BUCKET];
    __shared__ int lcnt[N_BUCKET];
    const int t  = threadIdx.x;
    const int me = blockIdx.x;

    int total = 0, before = 0;
    for (int blk = 0; blk < HBLK; ++blk) {
        const int v = blkhist[blk * N_BUCKET + t];
        total += v;
        if (blk < me) before += v;
    }
    scan_s[t] = total;
    __syncthreads();
    #pragma unroll
    for (int d = 1; d < N_BUCKET; d <<= 1) {
        const int v = (t >= d) ? scan_s[t - d] : 0;
        __syncthreads();
        scan_s[t] += v;
        __syncthreads();
    }
    const int gbase = scan_s[t] - total;
    bb[t]   = gbase + before;
    lcnt[t] = 0;
    if (me == 0) { offsets_g[t] = gbase; totals_g[t] = total; }
    __syncthreads();

    const int base = me * HEPB;
    #pragma unroll
    for (int k = 0; k < HEPB / 1024; ++k) {
        const int e = base + k * 1024 + t;
        const int seg = (cidx[e] << 2) | sidx[e];
        const int bkt = seg >> 7;
        const int r = atomicAdd(&lcnt[bkt], 1);
        records[bb[bkt] + r] = ((unsigned)(seg & 127) << 20) | (unsigned)e;
    }
}

__global__ __launch_bounds__(256) void compute4_kernel(
    const unsigned int* __restrict__ sorted_rec,
    const int* __restrict__ offsets, const int* __restrict__ counts,
    const float* __restrict__ vectors,
    const float* __restrict__ rw, float* __restrict__ out)
{
    __shared__ float4 pay[CAP];
    __shared__ int shist[SEG_PER_B];
    __shared__ int soff[SEG_PER_B];
    __shared__ int scur[SEG_PER_B];

    const int t = threadIdx.x;
    const int b = blockIdx.x;
    const int n = t & 7;
    const int g = t >> 3;

    float Wn[4][N_BASIS];
    #pragma unroll
    for (int l = 0; l < 4; ++l)
        #pragma unroll
        for (int bb = 0; bb < N_BASIS; ++bb)
            Wn[l][bb] = rw[(l * N_BASIS + bb) * 8 + n];

    const int off = offsets[b];
    const int cnt = counts[b];

    if (cnt > CAP) {
        #pragma unroll 1
        for (int k = 0; k < 4; ++k) {
            const int sl = g * 4 + k;
            float acc[16];
            #pragma unroll
            for (int L = 0; L < 16; ++L) acc[L] = 0.0f;
            for (int j = 0; j < cnt; ++j) {
                const unsigned rec = sorted_rec[off + j];
                if ((int)(rec >> 20) != sl) continue;
                const int eid = rec & 0xFFFFF;
                const float4 v = make_float4(vectors[3*eid], vectors[3*eid+1],
                                             vectors[3*eid+2], 0.0f);
                accum_edge(v, Wn, acc);
            }
            flush_seg(acc, b, sl, n, out);
        }
        return;
    }

    if (t < SEG_PER_B) shist[t] = 0;
    __syncthreads();

    unsigned recs[6];
    const int iters = (cnt + 255) >> 8;
    #pragma unroll
    for (int it = 0; it < 6; ++it) {
        const int i = it * 256 + t;
        if (it < iters && i < cnt) {
            recs[it] = sorted_rec[off + i];
            atomicAdd(&shist[recs[it] >> 20], 1);
        }
    }
    __syncthreads();

    if (t < SEG_PER_B) soff[t] = shist[t];
    __syncthreads();
    #pragma unroll
    for (int d = 1; d < SEG_PER_B; d <<= 1) {
        int v = 0;
        if (t >= d && t < SEG_PER_B) v = soff[t - d];
        __syncthreads();
        if (t < SEG_PER_B) soff[t] += v;
        __syncthreads();
    }
    if (t < SEG_PER_B) {
        const int ex = soff[t] - shist[t];
        soff[t] = ex;
        scur[t] = ex;
    }
    __syncthreads();

    #pragma unroll
    for (int it = 0; it < 6; ++it) {
        const int i = it * 256 + t;
        if (it < iters && i < cnt) {
            const unsigned rec = recs[it];
            const int sl  = rec >> 20;
            const int eid = rec & 0xFFFFF;
            const int r = atomicAdd(&scur[sl], 1);
            pay[r] = make_float4(vectors[3 * eid], vectors[3 * eid + 1],
                                 vectors[3 * eid + 2], __int_as_float(sl));
        }
    }
    __syncthreads();

    const int s0 = g * 4;
    const int js = soff[s0];
    const int je = (s0 + 4 < SEG_PER_B) ? soff[s0 + 4] : cnt;

    int cur = -1;
    float acc[16];
    #pragma unroll
    for (int L = 0; L < 16; ++L) acc[L] = 0.0f;

    for (int j = js; j < je; ++j) {
        const float4 v = pay[j];
        const int sl = __float_as_int(v.w);
        if (sl != cur) {
            if (cur >= 0) {
                flush_seg(acc, b, cur, n, out);
                #pragma unroll
                for (int L = 0; L < 16; ++L) acc[L] = 0.0f;
            }
            cur = sl;
        }
        accum_edge(v, Wn, acc);
    }
    if (cur >= 0) flush_seg(acc, b, cur, n, out);

    #pragma unroll
    for (int k = 0; k < 4; ++k) {
        const int sl = s0 + k;
        if (shist[sl] == 0) {
            float z[16];
            #pragma unroll
            for (int L = 0; L < 16; ++L) z[L] = 0.0f;
            flush_seg(z, b, sl, n, out);
        }
    }
}

// ---------- deep fallback: atomic kernel (ws too small) ----------
__global__ __launch_bounds__(256) void atomic_kernel(
    const float* __restrict__ vectors, const float* __restrict__ rw,
    const int* __restrict__ cidx, const int* __restrict__ sidx,
    float* __restrict__ out)
{
    const int e = blockIdx.x * 256 + threadIdx.x;
    if (e >= N_EDGES) return;
    float ph[N_BASIS], sh[16];
    compute_edge(vectors[3*e], vectors[3*e+1], vectors[3*e+2], ph, sh);
    float* op = out + (size_t)cidx[e] * 512 + sidx[e] * 8;
    for (int l = 0; l < 4; ++l) {
        const int L0 = l * l;
        const int ml = 2 * l + 1;
        for (int nn = 0; nn < 8; ++nn) {
            float rad = 0.0f;
            for (int bb = 0; bb < N_BASIS; ++bb)
                rad = fmaf(ph[bb], rw[(l * N_BASIS + bb) * 8 + nn], rad);
            for (int mm = 0; mm < ml; ++mm)
                atomicAdd(op + (L0 + mm) * 32 + nn, sh[L0 + mm] * rad);
        }
    }
}

extern "C" void kernel_launch(void* const* d_in, const int* in_sizes, int n_in,
                              void* d_out, int out_size, void* d_ws, size_t ws_size,
                              hipStream_t stream) {
    const float* vectors = (const float*)d_in[0];
    const float* rw      = (const float*)d_in[1];
    const int*   cidx    = (const int*)d_in[2];
    const int*   sidx    = (const int*)d_in[3];
    float*       out     = (float*)d_out;

    char* ws = (char*)d_ws;
    int* blkhist = (int*)(ws + WS_BLKHIST);
    int* totals  = (int*)(ws + WS_TOTALS);
    int* offsets = (int*)(ws + WS_OFFSETS);

    if (ws_size >= WS_NEED16) {
        float4* rec16 = (float4*)(ws + WS_REC);
        hipLaunchKernelGGL(hist_kernel,        dim3(HBLK),     dim3(1024), 0, stream, cidx, sidx, blkhist);
        hipLaunchKernelGGL(partition16_kernel, dim3(HBLK),     dim3(1024), 0, stream, cidx, sidx, vectors, blkhist, rec16, offsets, totals);
        hipLaunchKernelGGL(compute16_kernel,   dim3(N_BUCKET), dim3(256),  0, stream, rec16, offsets, totals, rw, out);
    } else if (ws_size >= WS_NEED4) {
        unsigned int* records = (unsigned int*)(ws + WS_REC);
        hipLaunchKernelGGL(hist_kernel,        dim3(HBLK),     dim3(1024), 0, stream, cidx, sidx, blkhist);
        hipLaunchKernelGGL(partition4_kernel,  dim3(HBLK),     dim3(1024), 0, stream, cidx, sidx, blkhist, records, offsets, totals);
        hipLaunchKernelGGL(compute4_kernel,    dim3(N_BUCKET), dim3(256),  0, stream, records, offsets, totals, vectors, rw, out);
    } else {
        hipMemsetAsync(out, 0, (size_t)out_size * sizeof(float), stream);
        hipLaunchKernelGGL(atomic_kernel, dim3(N_EDGES / 256), dim3(256), 0, stream,
                           vectors, rw, cidx, sidx, out);
    }
}